// Round 2
// baseline (6235.074 us; speedup 1.0000x reference)
//
#include <hip/hip_runtime.h>
#include <cstdint>
#include <cstddef>

#define DEV __device__ __forceinline__

typedef __attribute__((ext_vector_type(8))) short    short8;   // 8 bf16
typedef __attribute__((ext_vector_type(4))) float    f32x4;
typedef __attribute__((ext_vector_type(2))) _Float16 f16x2;
typedef __attribute__((ext_vector_type(8))) _Float16 f16x8;

static constexpr int B_ = 128, T_ = 1024, F_ = 128, H_ = 128, L_ = 7;
static constexpr int G4 = 512;           // 4*H
static constexpr int M_ = B_ * T_;       // 131072

// ---------- numeric helpers ----------
DEV float b2f(unsigned short u){ union{unsigned int i; float f;} v; v.i = ((unsigned)u)<<16; return v.f; }
DEV float b2f_lo(unsigned int u){ union{unsigned int i; float f;} v; v.i = u<<16; return v.f; }
DEV float b2f_hi(unsigned int u){ union{unsigned int i; float f;} v; v.i = u & 0xffff0000u; return v.f; }
DEV unsigned short f2b(float f){
  union{float f; unsigned int i;} v; v.f = f;
  unsigned int r = v.i + 0x7FFF + ((v.i >> 16) & 1);
  return (unsigned short)(r >> 16);
}
DEV float fexp2(float x){
#if __has_builtin(__builtin_amdgcn_exp2f)
  return __builtin_amdgcn_exp2f(x);
#else
  return exp2f(x);
#endif
}
DEV float frcp(float x){
#if __has_builtin(__builtin_amdgcn_rcpf)
  return __builtin_amdgcn_rcpf(x);
#else
  return 1.0f/x;
#endif
}
DEV float fsig(float x){ return frcp(1.f + fexp2(-1.44269504f*x)); }
DEV float ftanh(float x){
  x = fminf(10.f, fmaxf(-10.f, x));
  float e = fexp2(2.88539008f*x);
  return (e - 1.f) * frcp(e + 1.f);
}
DEV float fdot2(f16x2 a, f16x2 b, float c){
#if __has_builtin(__builtin_amdgcn_fdot2)
  return __builtin_amdgcn_fdot2(a, b, c, false);
#else
  return c + (float)a[0]*(float)b[0] + (float)a[1]*(float)b[1];
#endif
}

// ---------- converts ----------
__global__ void k_cvt_x(const float4* __restrict__ x4, ushort4* __restrict__ xb4, int n4){
  int i = blockIdx.x*blockDim.x + threadIdx.x;
  int stride = gridDim.x*blockDim.x;
  for (; i < n4; i += stride){
    float4 v = x4[i];
    ushort4 o; o.x = f2b(v.x); o.y = f2b(v.y); o.z = f2b(v.z); o.w = f2b(v.w);
    xb4[i] = o;
  }
}

__global__ void k_cvt_w(const float* __restrict__ Wih, const float* __restrict__ Whh,
                        const float* __restrict__ bih, const float* __restrict__ bhh,
                        unsigned short* __restrict__ wihb, _Float16* __restrict__ whhh,
                        float* __restrict__ bias){
  int i = blockIdx.x*blockDim.x + threadIdx.x;
  const int nw = L_*G4*F_;                       // 458752
  int stride = gridDim.x*blockDim.x;
  for (int k = i; k < nw; k += stride){
    wihb[k] = f2b(Wih[k]);
    whhh[k] = (_Float16)Whh[k];
  }
  if (i < L_*G4) bias[i] = bih[i] + bhh[i];
}

// ---------- GEMM: xg[M,512] = in[M,128] * Wih^T + bias ----------
template<bool XGF32>
__global__ __launch_bounds__(256) void k_gemm(const unsigned short* __restrict__ A,
                                              const unsigned short* __restrict__ W,
                                              const float* __restrict__ bias,
                                              void* __restrict__ xgv){
  int bid = blockIdx.x;
  int xcd = bid & 7;
  int j   = bid >> 3;
  int mt  = xcd*128 + (j >> 3);   // [0,1024) 128-row tiles; XCD-local streaming
  int nt  = j & 7;                // [0,8) 64-col tiles
  int wv  = threadIdx.x >> 6;
  int lane = threadIdx.x & 63;
  int lr = lane & 15, lk = lane >> 4;
  int m0 = mt*128 + wv*32;
  int n0 = nt*64;
  const unsigned short* a0p = A + (size_t)(m0 + lr)*F_ + lk*8;
  const unsigned short* b0p = W + (size_t)(n0 + lr)*F_ + lk*8;
  f32x4 acc[2][4] = {};
#pragma unroll
  for (int kt = 0; kt < 4; ++kt){
    short8 a0 = *(const short8*)(a0p + kt*32);
    short8 a1 = *(const short8*)(a0p + 16*F_ + kt*32);
    short8 w0 = *(const short8*)(b0p + kt*32);
    short8 w1 = *(const short8*)(b0p + 16*F_ + kt*32);
    short8 w2 = *(const short8*)(b0p + 32*F_ + kt*32);
    short8 w3 = *(const short8*)(b0p + 48*F_ + kt*32);
    acc[0][0] = __builtin_amdgcn_mfma_f32_16x16x32_bf16(a0, w0, acc[0][0], 0, 0, 0);
    acc[0][1] = __builtin_amdgcn_mfma_f32_16x16x32_bf16(a0, w1, acc[0][1], 0, 0, 0);
    acc[0][2] = __builtin_amdgcn_mfma_f32_16x16x32_bf16(a0, w2, acc[0][2], 0, 0, 0);
    acc[0][3] = __builtin_amdgcn_mfma_f32_16x16x32_bf16(a0, w3, acc[0][3], 0, 0, 0);
    acc[1][0] = __builtin_amdgcn_mfma_f32_16x16x32_bf16(a1, w0, acc[1][0], 0, 0, 0);
    acc[1][1] = __builtin_amdgcn_mfma_f32_16x16x32_bf16(a1, w1, acc[1][1], 0, 0, 0);
    acc[1][2] = __builtin_amdgcn_mfma_f32_16x16x32_bf16(a1, w2, acc[1][2], 0, 0, 0);
    acc[1][3] = __builtin_amdgcn_mfma_f32_16x16x32_bf16(a1, w3, acc[1][3], 0, 0, 0);
  }
  float bcol[4];
#pragma unroll
  for (int nf = 0; nf < 4; ++nf) bcol[nf] = bias[n0 + nf*16 + lr];
#pragma unroll
  for (int mf = 0; mf < 2; ++mf)
#pragma unroll
    for (int nf = 0; nf < 4; ++nf)
#pragma unroll
      for (int r = 0; r < 4; ++r){
        int row = m0 + mf*16 + lk*4 + r;
        int col = n0 + nf*16 + lr;
        float v = acc[mf][nf][r] + bcol[nf];
        if constexpr (XGF32) ((float*)xgv)[(size_t)row*G4 + col] = v;
        else ((unsigned short*)xgv)[(size_t)row*G4 + col] = f2b(v);
      }
}

// ---------- recurrence: one workgroup per batch element ----------
// 8 waves; wave w lane l -> h-row r = w*16 + (l>>2), gate q = l&3,
// gate row g = q*128 + r (PyTorch gate order i,f,g,o).
// Per step: dot(w_row, h) per thread; shuffle-gather the 4 gate z's inside
// the 4-lane group; all 4 lanes redundantly compute c,h; lane q==0 writes h.
// Double-buffered hsh -> ONE barrier per step, and the barrier is a raw
// s_waitcnt lgkmcnt(0)+s_barrier (NO vmcnt drain: xg prefetch loads and hout
// stores are thread-private, they may stay in flight across the barrier).
template<bool XGF32>
__global__ __launch_bounds__(512) void k_recur(const void* __restrict__ xgv,
                                               const _Float16* __restrict__ Wh,
                                               unsigned short* __restrict__ hout){
  int b = blockIdx.x;
  int tid = threadIdx.x;
  int w = tid >> 6, l = tid & 63;
  int r = w*16 + (l >> 2);
  int q = l & 3;
  int g = q*H_ + r;
  __shared__ __align__(16) _Float16 hsh[2][H_];

  // weights for this gate row: 64 x f16x2 in VGPRs
  f16x2 wreg[64];
  const f16x2* wrow = (const f16x2*)(Wh + (size_t)g*H_);
#pragma unroll
  for (int k = 0; k < 64; ++k) wreg[k] = wrow[k];

  if (tid < H_) hsh[0][tid] = (_Float16)0.f;
  float c = 0.f;

  const float*          xf = (const float*)xgv          + (size_t)b*T_*G4 + g;
  const unsigned short* xb = (const unsigned short*)xgv + (size_t)b*T_*G4 + g;
  auto loadx = [&](int t) -> float {
    if constexpr (XGF32) return xf[(size_t)t*G4];
    else                 return b2f(xb[(size_t)t*G4]);
  };
  // 4-deep prefetch ring
  float xq0 = loadx(0), xq1 = loadx(1), xq2 = loadx(2), xq3 = loadx(3);
  __syncthreads();

  int buf = 0;
  for (int t = 0; t < T_; ++t){
    const _Float16* hp = hsh[buf];
    // 4 split accumulators to shorten the dependent chain
    float a0 = xq0, a1 = 0.f, a2 = 0.f, a3 = 0.f;
#pragma unroll
    for (int k8 = 0; k8 < 8; ++k8){
      f16x8 hv = *(const f16x8*)(hp + k8*8);
      f16x2 p0 = __builtin_shufflevector(hv, hv, 0, 1);
      f16x2 p1 = __builtin_shufflevector(hv, hv, 2, 3);
      f16x2 p2 = __builtin_shufflevector(hv, hv, 4, 5);
      f16x2 p3 = __builtin_shufflevector(hv, hv, 6, 7);
      a0 = fdot2(p0, wreg[k8*4+0], a0);
      a1 = fdot2(p1, wreg[k8*4+1], a1);
      a2 = fdot2(p2, wreg[k8*4+2], a2);
      a3 = fdot2(p3, wreg[k8*4+3], a3);
    }
    float z = (a0 + a1) + (a2 + a3);
    // rotate prefetch ring (loads stay in flight across the raw barrier)
    xq0 = xq1; xq1 = xq2; xq2 = xq3;
    xq3 = (t + 4 < T_) ? loadx(t + 4) : 0.f;
    // gather the 4 gates of row r from the 4-lane group
    int base = l & ~3;
    float zi = __shfl(z, base + 0);
    float zf = __shfl(z, base + 1);
    float zg = __shfl(z, base + 2);
    float zo = __shfl(z, base + 3);
    // redundant compute in all 4 lanes (issue cost identical, no divergence)
    c = fsig(zf)*c + fsig(zi)*ftanh(zg);
    float h = fsig(zo)*ftanh(c);
    if (q == 0){
      hsh[buf ^ 1][r] = (_Float16)h;
      hout[(size_t)(b*T_ + t)*H_ + r] = f2b(h);
    }
    // raw barrier: wait LDS ops only; vmcnt intentionally NOT drained
    asm volatile("s_waitcnt lgkmcnt(0)\n\ts_barrier" ::: "memory");
    buf ^= 1;
  }
}

// ---------- attention (only head A-1 matters) + final linear + sigmoid ----------
__global__ __launch_bounds__(256) void k_attn(const unsigned short* __restrict__ out,
                                              const float* __restrict__ Wa, const float* __restrict__ ba,
                                              const float* __restrict__ Wf, const float* __restrict__ bfv,
                                              float* __restrict__ y){
  int b = blockIdx.x, tid = threadIdx.x;
  __shared__ float was[H_];
  __shared__ float p[T_];
  __shared__ float red[64];
  __shared__ float app[256];
  if (tid < H_) was[tid] = Wa[127*H_ + tid];
  __syncthreads();
  float bav = ba[127];
  // scores
  for (int t = tid; t < T_; t += 256){
    const unsigned short* row = out + (size_t)(b*T_ + t)*H_;
    float acc = 0.f;
#pragma unroll
    for (int k = 0; k < H_; k += 8){
      uint4 u = *(const uint4*)(row + k);
      acc += b2f_lo(u.x)*was[k+0] + b2f_hi(u.x)*was[k+1];
      acc += b2f_lo(u.y)*was[k+2] + b2f_hi(u.y)*was[k+3];
      acc += b2f_lo(u.z)*was[k+4] + b2f_hi(u.z)*was[k+5];
      acc += b2f_lo(u.w)*was[k+6] + b2f_hi(u.w)*was[k+7];
    }
    p[t] = ftanh(acc + bav);
  }
  __syncthreads();
  // max over time
  float m = -1e30f;
  for (int t = tid; t < T_; t += 256) m = fmaxf(m, p[t]);
  for (int off = 32; off; off >>= 1) m = fmaxf(m, __shfl_xor(m, off));
  if ((tid & 63) == 0) red[tid >> 6] = m;
  __syncthreads();
  if (tid == 0) red[8] = fmaxf(fmaxf(red[0], red[1]), fmaxf(red[2], red[3]));
  __syncthreads();
  float smax = red[8];
  float lsum = 0.f;
  for (int t = tid; t < T_; t += 256){
    float e = fexp2(1.44269504f*(p[t] - smax));
    p[t] = e; lsum += e;
  }
  for (int off = 32; off; off >>= 1) lsum += __shfl_xor(lsum, off);
  if ((tid & 63) == 0) red[16 + (tid >> 6)] = lsum;
  __syncthreads();
  float rden = frcp(red[16] + red[17] + red[18] + red[19]);
  // weighted sum over time: thread tid -> h = tid&127, t-half = tid>>7
  int h = tid & (H_ - 1);
  int half = tid >> 7;
  float acc = 0.f;
  for (int t = half*512; t < half*512 + 512; ++t)
    acc += p[t] * b2f(out[(size_t)(b*T_ + t)*H_ + h]);
  app[tid] = acc;
  __syncthreads();
  if (tid < H_){
    float applied = (app[tid] + app[tid + H_]) * rden;
    float v = applied * Wf[tid];
    for (int off = 32; off; off >>= 1) v += __shfl_xor(v, off);
    if (tid == 0)  red[32] = v;
    if (tid == 64) red[33] = v;
  }
  __syncthreads();
  if (tid == 0) y[b] = fsig(red[32] + red[33] + bfv[0]);
}

// ---------- launch ----------
extern "C" void kernel_launch(void* const* d_in, const int* in_sizes, int n_in,
                              void* d_out, int out_size, void* d_ws, size_t ws_size,
                              hipStream_t stream){
  const float* x   = (const float*)d_in[0];
  const float* Wih = (const float*)d_in[1];
  const float* Whh = (const float*)d_in[2];
  const float* bih = (const float*)d_in[3];
  const float* bhh = (const float*)d_in[4];
  const float* Wa  = (const float*)d_in[5];
  const float* ba  = (const float*)d_in[6];
  const float* Wf  = (const float*)d_in[7];
  const float* bfv = (const float*)d_in[8];
  float* y = (float*)d_out;

  char* ws = (char*)d_ws;
  size_t off = 0;
  auto alloc = [&](size_t bytes) -> void* {
    void* p = ws + off; off += (bytes + 255) & ~(size_t)255; return p;
  };
  unsigned short* wihb = (unsigned short*)alloc((size_t)L_*G4*F_*2);
  _Float16*       whhh = (_Float16*)      alloc((size_t)L_*G4*F_*2);
  float*          bias = (float*)         alloc((size_t)L_*G4*4);
  unsigned short* bufA = (unsigned short*)alloc((size_t)M_*H_*2);
  unsigned short* bufB = (unsigned short*)alloc((size_t)M_*H_*2);
  size_t xg_f32_bytes = (size_t)M_*G4*4;
  bool xgf32 = (off + xg_f32_bytes) <= ws_size;
  void* xg = alloc(xgf32 ? xg_f32_bytes : xg_f32_bytes/2);

  k_cvt_x<<<2048, 256, 0, stream>>>((const float4*)x, (ushort4*)bufA, M_*F_/4);
  k_cvt_w<<<1792, 256, 0, stream>>>(Wih, Whh, bih, bhh, wihb, whhh, bias);

  const unsigned short* cur = bufA;
  unsigned short* nxt = bufB;
  for (int l = 0; l < L_; ++l){
    const unsigned short* wl  = wihb + (size_t)l*G4*F_;
    const _Float16*       whl = whhh + (size_t)l*G4*F_;
    const float*          bl  = bias + l*G4;
    if (xgf32){
      k_gemm<true ><<<8192, 256, 0, stream>>>(cur, wl, bl, xg);
      k_recur<true ><<<128, 512, 0, stream>>>(xg, whl, nxt);
    } else {
      k_gemm<false><<<8192, 256, 0, stream>>>(cur, wl, bl, xg);
      k_recur<false><<<128, 512, 0, stream>>>(xg, whl, nxt);
    }
    const unsigned short* tmp = cur; cur = nxt; nxt = (unsigned short*)const_cast<unsigned short*>(tmp);
  }
  k_attn<<<128, 256, 0, stream>>>(cur, Wa, ba, Wf, bfv, y);
}

// Round 3
// 4959.755 us; speedup vs baseline: 1.2571x; 1.2571x over previous
//
#include <hip/hip_runtime.h>
#include <cstdint>
#include <cstddef>

#define DEV __device__ __forceinline__

typedef __attribute__((ext_vector_type(8))) short    short8;   // 8 bf16
typedef __attribute__((ext_vector_type(4))) float    f32x4;
typedef __attribute__((ext_vector_type(8))) _Float16 f16x8;

static constexpr int B_ = 128, T_ = 1024, F_ = 128, H_ = 128, L_ = 7;
static constexpr int G4 = 512;           // 4*H
static constexpr int M_ = B_ * T_;       // 131072

// ---------- numeric helpers ----------
DEV float b2f(unsigned short u){ union{unsigned int i; float f;} v; v.i = ((unsigned)u)<<16; return v.f; }
DEV float b2f_lo(unsigned int u){ union{unsigned int i; float f;} v; v.i = u<<16; return v.f; }
DEV float b2f_hi(unsigned int u){ union{unsigned int i; float f;} v; v.i = u & 0xffff0000u; return v.f; }
DEV unsigned short f2b(float f){
  union{float f; unsigned int i;} v; v.f = f;
  unsigned int r = v.i + 0x7FFF + ((v.i >> 16) & 1);
  return (unsigned short)(r >> 16);
}
DEV float fexp2(float x){
#if __has_builtin(__builtin_amdgcn_exp2f)
  return __builtin_amdgcn_exp2f(x);
#else
  return exp2f(x);
#endif
}
DEV float frcp(float x){
#if __has_builtin(__builtin_amdgcn_rcpf)
  return __builtin_amdgcn_rcpf(x);
#else
  return 1.0f/x;
#endif
}
DEV float fsig(float x){ return frcp(1.f + fexp2(-1.44269504f*x)); }
DEV float ftanh(float x){
  x = fminf(10.f, fmaxf(-10.f, x));
  float e = fexp2(2.88539008f*x);
  return (e - 1.f) * frcp(e + 1.f);
}

// ---------- converts ----------
__global__ void k_cvt_x(const float4* __restrict__ x4, ushort4* __restrict__ xb4, int n4){
  int i = blockIdx.x*blockDim.x + threadIdx.x;
  int stride = gridDim.x*blockDim.x;
  for (; i < n4; i += stride){
    float4 v = x4[i];
    ushort4 o; o.x = f2b(v.x); o.y = f2b(v.y); o.z = f2b(v.z); o.w = f2b(v.w);
    xb4[i] = o;
  }
}

__global__ void k_cvt_w(const float* __restrict__ Wih, const float* __restrict__ Whh,
                        const float* __restrict__ bih, const float* __restrict__ bhh,
                        unsigned short* __restrict__ wihb, _Float16* __restrict__ whhh,
                        float* __restrict__ bias){
  int i = blockIdx.x*blockDim.x + threadIdx.x;
  const int nw = L_*G4*F_;                       // 458752
  int stride = gridDim.x*blockDim.x;
  for (int k = i; k < nw; k += stride){
    wihb[k] = f2b(Wih[k]);
    whhh[k] = (_Float16)Whh[k];
  }
  if (i < L_*G4) bias[i] = bih[i] + bhh[i];
}

// ---------- GEMM: xg[M,512] = in[M,128] * Wih^T + bias ----------
template<bool XGF32>
__global__ __launch_bounds__(256) void k_gemm(const unsigned short* __restrict__ A,
                                              const unsigned short* __restrict__ W,
                                              const float* __restrict__ bias,
                                              void* __restrict__ xgv){
  int bid = blockIdx.x;
  int xcd = bid & 7;
  int j   = bid >> 3;
  int mt  = xcd*128 + (j >> 3);   // [0,1024) 128-row tiles; XCD-local streaming
  int nt  = j & 7;                // [0,8) 64-col tiles
  int wv  = threadIdx.x >> 6;
  int lane = threadIdx.x & 63;
  int lr = lane & 15, lk = lane >> 4;
  int m0 = mt*128 + wv*32;
  int n0 = nt*64;
  const unsigned short* a0p = A + (size_t)(m0 + lr)*F_ + lk*8;
  const unsigned short* b0p = W + (size_t)(n0 + lr)*F_ + lk*8;
  f32x4 acc[2][4] = {};
#pragma unroll
  for (int kt = 0; kt < 4; ++kt){
    short8 a0 = *(const short8*)(a0p + kt*32);
    short8 a1 = *(const short8*)(a0p + 16*F_ + kt*32);
    short8 w0 = *(const short8*)(b0p + kt*32);
    short8 w1 = *(const short8*)(b0p + 16*F_ + kt*32);
    short8 w2 = *(const short8*)(b0p + 32*F_ + kt*32);
    short8 w3 = *(const short8*)(b0p + 48*F_ + kt*32);
    acc[0][0] = __builtin_amdgcn_mfma_f32_16x16x32_bf16(a0, w0, acc[0][0], 0, 0, 0);
    acc[0][1] = __builtin_amdgcn_mfma_f32_16x16x32_bf16(a0, w1, acc[0][1], 0, 0, 0);
    acc[0][2] = __builtin_amdgcn_mfma_f32_16x16x32_bf16(a0, w2, acc[0][2], 0, 0, 0);
    acc[0][3] = __builtin_amdgcn_mfma_f32_16x16x32_bf16(a0, w3, acc[0][3], 0, 0, 0);
    acc[1][0] = __builtin_amdgcn_mfma_f32_16x16x32_bf16(a1, w0, acc[1][0], 0, 0, 0);
    acc[1][1] = __builtin_amdgcn_mfma_f32_16x16x32_bf16(a1, w1, acc[1][1], 0, 0, 0);
    acc[1][2] = __builtin_amdgcn_mfma_f32_16x16x32_bf16(a1, w2, acc[1][2], 0, 0, 0);
    acc[1][3] = __builtin_amdgcn_mfma_f32_16x16x32_bf16(a1, w3, acc[1][3], 0, 0, 0);
  }
  float bcol[4];
#pragma unroll
  for (int nf = 0; nf < 4; ++nf) bcol[nf] = bias[n0 + nf*16 + lr];
#pragma unroll
  for (int mf = 0; mf < 2; ++mf)
#pragma unroll
    for (int nf = 0; nf < 4; ++nf)
#pragma unroll
      for (int r = 0; r < 4; ++r){
        int row = m0 + mf*16 + lk*4 + r;
        int col = n0 + nf*16 + lr;
        float v = acc[mf][nf][r] + bcol[nf];
        if constexpr (XGF32) ((float*)xgv)[(size_t)row*G4 + col] = v;
        else ((unsigned short*)xgv)[(size_t)row*G4 + col] = f2b(v);
      }
}

// ---------- recurrence: MFMA-broadcast design ----------
// One WG (8 waves, 512 thr) per batch element. Wave w owns h-rows [16w,16w+16).
// z = Whh·h via mfma_f32_16x16x32_f16 with B = h replicated across 16 columns
// (B-frag = broadcast ds_read_b128 of h[kk*32+8q .. +8]).
// A-row ordering m = 4*rowoff + gate puts ALL FOUR GATES of one h-row into one
// lane's f32x4 accumulator -> in-lane gate math, no shuffles, no z round-trip.
// Lane (q,i): consumes tile tau* = i&3 -> h-row 16w + 4*(i&3) + q (4x redundant).
// Writers: lanes i<4. One lgkmcnt-only barrier per step; xg loads prefetched
// 2 steps ahead and never drained by the barrier.
template<bool XGF32>
__global__ __launch_bounds__(512) void k_recur(const void* __restrict__ xgv,
                                               const _Float16* __restrict__ Wh,
                                               unsigned short* __restrict__ hout){
  const int b = blockIdx.x;
  const int tid = threadIdx.x;
  const int w = tid >> 6, l = tid & 63;
  const int q = l >> 4, i = l & 15;
  const int gsel = i & 3;         // as A-row: gate index; as consumer: tile select
  const int rbit = i >> 2;        // as A-row: row offset within 4-row group
  const int myrow = 16*w + 4*gsel + q;   // h-row this lane's gate-math handles

  __shared__ __align__(16) _Float16 hsh[2][H_];

  // Whh A-frags: A[m=i, k=8q+j] for tile (tau,kk)
  //   = Whh[gate=(i&3)][h-row = 16w + 4*tau + (i>>2)][k = kk*32 + 8q + j]
  f16x8 wf[4][4];
  {
    const _Float16* base = Wh + ((size_t)gsel*H_ + 16*w + rbit)*H_ + 8*q;
#pragma unroll
    for (int tau = 0; tau < 4; ++tau)
#pragma unroll
      for (int kk = 0; kk < 4; ++kk)
        wf[tau][kk] = *(const f16x8*)(base + (size_t)(4*tau)*H_ + kk*32);
  }

  if (tid < H_) hsh[0][tid] = (_Float16)0.f;
  float c = 0.f;

  const float*          xf = (const float*)xgv          + (size_t)b*T_*G4 + myrow;
  const unsigned short* xb = (const unsigned short*)xgv + (size_t)b*T_*G4 + myrow;
  auto ldx = [&](int t, int r) -> float {
    if constexpr (XGF32) return xf[(size_t)t*G4 + r*H_];
    else                 return b2f(xb[(size_t)t*G4 + r*H_]);
  };
  float x0[4], x1[4];
#pragma unroll
  for (int r = 0; r < 4; ++r){ x0[r] = ldx(0, r); x1[r] = ldx(1, r); }

  const bool c0 = (gsel & 1) != 0, c1 = (gsel & 2) != 0;
  const f32x4 vzero = {0.f, 0.f, 0.f, 0.f};

  __syncthreads();

  int buf = 0;
  for (int t = 0; t < T_; ++t){
    const _Float16* hp = hsh[buf];
    f16x8 h0 = *(const f16x8*)(hp + 0*32 + 8*q);
    f16x8 h1 = *(const f16x8*)(hp + 1*32 + 8*q);
    f16x8 h2 = *(const f16x8*)(hp + 2*32 + 8*q);
    f16x8 h3 = *(const f16x8*)(hp + 3*32 + 8*q);
    f32x4 aA[4], aB[4];
#pragma unroll
    for (int tau = 0; tau < 4; ++tau){
      f32x4 u = __builtin_amdgcn_mfma_f32_16x16x32_f16(wf[tau][0], h0, vzero, 0, 0, 0);
      u       = __builtin_amdgcn_mfma_f32_16x16x32_f16(wf[tau][1], h1, u,     0, 0, 0);
      f32x4 v = __builtin_amdgcn_mfma_f32_16x16x32_f16(wf[tau][2], h2, vzero, 0, 0, 0);
      v       = __builtin_amdgcn_mfma_f32_16x16x32_f16(wf[tau][3], h3, v,     0, 0, 0);
      aA[tau] = u; aB[tau] = v;
    }
    // select tile tau* = gsel: acc[tau*][r] = gate r of row myrow
    f32x4 sA = c1 ? (c0 ? aA[3] : aA[2]) : (c0 ? aA[1] : aA[0]);
    f32x4 sB = c1 ? (c0 ? aB[3] : aB[2]) : (c0 ? aB[1] : aB[0]);
    float zi = sA[0] + sB[0] + x0[0];
    float zf = sA[1] + sB[1] + x0[1];
    float zg = sA[2] + sB[2] + x0[2];
    float zo = sA[3] + sB[3] + x0[3];
    // rotate 2-deep prefetch (loads stay in flight across the barrier)
    int tc = (t + 2 < T_) ? t + 2 : T_ - 1;
#pragma unroll
    for (int r = 0; r < 4; ++r){ x0[r] = x1[r]; x1[r] = ldx(tc, r); }

    c = fsig(zf)*c + fsig(zi)*ftanh(zg);
    float h = fsig(zo)*ftanh(c);
    if (i < 4){                       // 16 writer lanes/wave, rows 16w+4i+q
      hsh[buf ^ 1][myrow] = (_Float16)h;
      hout[(size_t)(b*T_ + t)*H_ + myrow] = f2b(h);
    }
    asm volatile("s_waitcnt lgkmcnt(0)\n\ts_barrier" ::: "memory");
    buf ^= 1;
  }
}

// ---------- attention (only head A-1 matters) + final linear + sigmoid ----------
__global__ __launch_bounds__(256) void k_attn(const unsigned short* __restrict__ out,
                                              const float* __restrict__ Wa, const float* __restrict__ ba,
                                              const float* __restrict__ Wf, const float* __restrict__ bfv,
                                              float* __restrict__ y){
  int b = blockIdx.x, tid = threadIdx.x;
  __shared__ float was[H_];
  __shared__ float p[T_];
  __shared__ float red[64];
  __shared__ float app[256];
  if (tid < H_) was[tid] = Wa[127*H_ + tid];
  __syncthreads();
  float bav = ba[127];
  for (int t = tid; t < T_; t += 256){
    const unsigned short* row = out + (size_t)(b*T_ + t)*H_;
    float acc = 0.f;
#pragma unroll
    for (int k = 0; k < H_; k += 8){
      uint4 u = *(const uint4*)(row + k);
      acc += b2f_lo(u.x)*was[k+0] + b2f_hi(u.x)*was[k+1];
      acc += b2f_lo(u.y)*was[k+2] + b2f_hi(u.y)*was[k+3];
      acc += b2f_lo(u.z)*was[k+4] + b2f_hi(u.z)*was[k+5];
      acc += b2f_lo(u.w)*was[k+6] + b2f_hi(u.w)*was[k+7];
    }
    p[t] = ftanh(acc + bav);
  }
  __syncthreads();
  float m = -1e30f;
  for (int t = tid; t < T_; t += 256) m = fmaxf(m, p[t]);
  for (int off = 32; off; off >>= 1) m = fmaxf(m, __shfl_xor(m, off));
  if ((tid & 63) == 0) red[tid >> 6] = m;
  __syncthreads();
  if (tid == 0) red[8] = fmaxf(fmaxf(red[0], red[1]), fmaxf(red[2], red[3]));
  __syncthreads();
  float smax = red[8];
  float lsum = 0.f;
  for (int t = tid; t < T_; t += 256){
    float e = fexp2(1.44269504f*(p[t] - smax));
    p[t] = e; lsum += e;
  }
  for (int off = 32; off; off >>= 1) lsum += __shfl_xor(lsum, off);
  if ((tid & 63) == 0) red[16 + (tid >> 6)] = lsum;
  __syncthreads();
  float rden = frcp(red[16] + red[17] + red[18] + red[19]);
  int h = tid & (H_ - 1);
  int half = tid >> 7;
  float acc = 0.f;
  for (int t = half*512; t < half*512 + 512; ++t)
    acc += p[t] * b2f(out[(size_t)(b*T_ + t)*H_ + h]);
  app[tid] = acc;
  __syncthreads();
  if (tid < H_){
    float applied = (app[tid] + app[tid + H_]) * rden;
    float v = applied * Wf[tid];
    for (int off = 32; off; off >>= 1) v += __shfl_xor(v, off);
    if (tid == 0)  red[32] = v;
    if (tid == 64) red[33] = v;
  }
  __syncthreads();
  if (tid == 0) y[b] = fsig(red[32] + red[33] + bfv[0]);
}

// ---------- launch ----------
extern "C" void kernel_launch(void* const* d_in, const int* in_sizes, int n_in,
                              void* d_out, int out_size, void* d_ws, size_t ws_size,
                              hipStream_t stream){
  const float* x   = (const float*)d_in[0];
  const float* Wih = (const float*)d_in[1];
  const float* Whh = (const float*)d_in[2];
  const float* bih = (const float*)d_in[3];
  const float* bhh = (const float*)d_in[4];
  const float* Wa  = (const float*)d_in[5];
  const float* ba  = (const float*)d_in[6];
  const float* Wf  = (const float*)d_in[7];
  const float* bfv = (const float*)d_in[8];
  float* y = (float*)d_out;

  char* ws = (char*)d_ws;
  size_t off = 0;
  auto alloc = [&](size_t bytes) -> void* {
    void* p = ws + off; off += (bytes + 255) & ~(size_t)255; return p;
  };
  unsigned short* wihb = (unsigned short*)alloc((size_t)L_*G4*F_*2);
  _Float16*       whhh = (_Float16*)      alloc((size_t)L_*G4*F_*2);
  float*          bias = (float*)         alloc((size_t)L_*G4*4);
  unsigned short* bufA = (unsigned short*)alloc((size_t)M_*H_*2);
  unsigned short* bufB = (unsigned short*)alloc((size_t)M_*H_*2);
  size_t xg_f32_bytes = (size_t)M_*G4*4;
  bool xgf32 = (off + xg_f32_bytes) <= ws_size;
  void* xg = alloc(xgf32 ? xg_f32_bytes : xg_f32_bytes/2);

  k_cvt_x<<<2048, 256, 0, stream>>>((const float4*)x, (ushort4*)bufA, M_*F_/4);
  k_cvt_w<<<1792, 256, 0, stream>>>(Wih, Whh, bih, bhh, wihb, whhh, bias);

  const unsigned short* cur = bufA;
  unsigned short* nxt = bufB;
  for (int l = 0; l < L_; ++l){
    const unsigned short* wl  = wihb + (size_t)l*G4*F_;
    const _Float16*       whl = whhh + (size_t)l*G4*F_;
    const float*          bl  = bias + l*G4;
    if (xgf32){
      k_gemm<true ><<<8192, 256, 0, stream>>>(cur, wl, bl, xg);
      k_recur<true ><<<128, 512, 0, stream>>>(xg, whl, nxt);
    } else {
      k_gemm<false><<<8192, 256, 0, stream>>>(cur, wl, bl, xg);
      k_recur<false><<<128, 512, 0, stream>>>(xg, whl, nxt);
    }
    const unsigned short* tmp = cur; cur = nxt; nxt = (unsigned short*)const_cast<unsigned short*>(tmp);
  }
  k_attn<<<128, 256, 0, stream>>>(cur, Wa, ba, Wf, bfv, y);
}